// Round 10
// baseline (38.942 us; speedup 1.0000x reference)
//
#include <hip/hip_runtime.h>

// Problem constants (from reference setup_inputs)
#define BB 4
#define CC 128
#define HH 256
#define WW 256
#define NKP 4096
#define INV_RATIO (1.0f / 16.0f)
#define CPT 4
#define NXCD 8

typedef float fpair __attribute__((ext_vector_type(2)));

// ws layout (bytes):
//   [0, 128K)        sorted_kp : BB*NKP float2 (scaled feature coords, sorted by line-id)
//   [128K, 192K)     inv       : BB*NKP u32 (sorted position of original index n)
//   [256K, 256K+8M)  out_sorted: BB*CC*NKP float (values in sorted order)
#define O_INV  (BB * NKP * 2 * 4)          // 131072
#define O_VS   (256 * 1024)                // 262144
#define WS_NEEDED (O_VS + (size_t)BB * CC * NKP * 4)

// ---------- K1: per-batch counting sort of keypoints by cache-line id ----------
__global__ __launch_bounds__(1024) void sort_kernel(
    const float* __restrict__ keypoints,   // B x N x 2
    float* __restrict__ sorted_kp,         // B x N x 2 (scaled)
    unsigned* __restrict__ inv)            // B x N
{
    __shared__ unsigned bins[4096];
    __shared__ unsigned wtot[16];
    __shared__ unsigned wexc[16];
    const int b = blockIdx.x;
    const int t = threadIdx.x;           // 0..1023
    const int lane = t & 63, wid = t >> 6;

    #pragma unroll
    for (int k = 0; k < 4; ++k) bins[t + 1024 * k] = 0u;
    __syncthreads();

    // histogram; key = y0*16 + x0/16 (line id of the lower-left corner)
    unsigned key[4];
    float kxv[4], kyv[4];
    #pragma unroll
    for (int k = 0; k < 4; ++k) {
        int n = t + 1024 * k;
        const float* kp = keypoints + ((size_t)(b * NKP + n)) * 2;
        float kx = kp[0] * INV_RATIO, ky = kp[1] * INV_RATIO;
        kxv[k] = kx; kyv[k] = ky;
        int x0 = (int)fmaxf(floorf(kx), 0.0f);
        int y0 = (int)fmaxf(floorf(ky), 0.0f);
        unsigned bin = ((unsigned)y0 << 4) | ((unsigned)x0 >> 4);
        key[k] = bin;
        atomicAdd(&bins[bin], 1u);
    }
    __syncthreads();

    // exclusive scan over 4096 bins; thread t owns bins[4t..4t+3]
    unsigned c0 = bins[4*t], c1 = bins[4*t+1], c2 = bins[4*t+2], c3 = bins[4*t+3];
    unsigned s = c0 + c1 + c2 + c3;
    unsigned v = s;
    #pragma unroll
    for (int d = 1; d < 64; d <<= 1) {
        unsigned u = __shfl_up(v, d, 64);
        if (lane >= d) v += u;
    }
    if (lane == 63) wtot[wid] = v;
    __syncthreads();
    if (t == 0) { unsigned acc = 0; for (int w = 0; w < 16; ++w) { wexc[w] = acc; acc += wtot[w]; } }
    __syncthreads();
    unsigned texc = wexc[wid] + (v - s);   // exclusive offset of this thread's 4 bins
    bins[4*t]   = texc;
    bins[4*t+1] = texc + c0;
    bins[4*t+2] = texc + c0 + c1;
    bins[4*t+3] = texc + c0 + c1 + c2;
    __syncthreads();

    // scatter: assign sorted positions; write scaled coords + inverse perm
    #pragma unroll
    for (int k = 0; k < 4; ++k) {
        int n = t + 1024 * k;
        unsigned pos = atomicAdd(&bins[key[k]], 1u);
        float* dst = sorted_kp + ((size_t)(b * NKP) + pos) * 2;
        dst[0] = kxv[k];
        dst[1] = kyv[k];
        inv[b * NKP + n] = pos;
    }
}

// ---------- K2: gather in sorted order (R8 math verbatim) ----------
__global__ __launch_bounds__(256) void gather_kernel(
    const float* __restrict__ feature,     // B x C x H x W
    const float* __restrict__ sorted_kp,   // B x N x 2 (scaled)
    float* __restrict__ out_sorted)        // B x C x N (sorted order)
{
    int bid   = blockIdx.x;        // 0..2047
    int xcd   = bid & (NXCD - 1);
    int slot  = bid >> 3;
    int gloc  = slot >> 4;
    int j     = slot & 15;
    int g     = gloc * NXCD + xcd; // 0..127
    int b     = g >> 5;
    int c0    = (g & 31) * CPT;
    int i     = j * 256 + threadIdx.x;     // sorted keypoint index

    fpair kpv;
    __builtin_memcpy(&kpv, sorted_kp + ((size_t)(b * NKP) + i) * 2, sizeof(fpair));
    float kx = kpv.x, ky = kpv.y;

    float fx = fmaxf(floorf(kx), 0.0f);
    float fy = fmaxf(floorf(ky), 0.0f);
    int x0 = (int)fx, y0 = (int)fy;

    float ux = kx - fx, uy = ky - fy;
    float lx = 1.0f - ux, ly = 1.0f - uy;

    bool selx = (x0 >= WW - 1);
    bool sely = (y0 >= HH - 1);
    int xp = selx ? (WW - 2) : x0;
    int yp = sely ? (HH - 2) : y0;
    float wlx = selx ? 0.0f : lx, wux = selx ? 1.0f : ux;
    float wly = sely ? 0.0f : ly, wuy = sely ? 1.0f : uy;

    float mask = 0.5f * ((kx > 1e-10f ? 1.0f : 0.0f) + (ky > 1e-10f ? 1.0f : 0.0f));
    float w00 = wlx * wly * mask, w01 = wux * wly * mask;
    float w10 = wlx * wuy * mask, w11 = wux * wuy * mask;

    int i0 = yp * WW + xp;
    int i1 = i0 + WW;

    const float* f = feature + ((size_t)(b * CC + c0)) * (HH * WW);

    fpair r0[CPT], r1[CPT];
    #pragma unroll
    for (int k = 0; k < CPT; ++k) {
        const float* fc = f + (size_t)k * (HH * WW);
        __builtin_memcpy(&r0[k], fc + i0, sizeof(fpair));
        __builtin_memcpy(&r1[k], fc + i1, sizeof(fpair));
    }

    float* o = out_sorted + ((size_t)(b * CC + c0)) * NKP + i;
    #pragma unroll
    for (int k = 0; k < CPT; ++k) {
        float val = w00 * r0[k].x + w01 * r0[k].y
                  + w10 * r1[k].x + w11 * r1[k].y;
        o[(size_t)k * NKP] = val;          // normal store: re-read by K3 soon
    }
}

// ---------- K3: permute each (b,c) row back to original keypoint order ----------
__global__ __launch_bounds__(256) void permute_kernel(
    const float* __restrict__ out_sorted,  // B x C x N (sorted order)
    const unsigned* __restrict__ inv,      // B x N
    float* __restrict__ out)               // B x C x N (original order)
{
    __shared__ float v[NKP];               // 16 KB
    int bc = blockIdx.x;                   // 0..511
    int b  = bc >> 7;                      // / CC
    const float* src = out_sorted + (size_t)bc * NKP;
    for (int k = threadIdx.x; k < NKP; k += 256) v[k] = src[k];
    __syncthreads();
    const unsigned* invb = inv + b * NKP;
    float* dst = out + (size_t)bc * NKP;
    for (int n = threadIdx.x; n < NKP; n += 256) {
        __builtin_nontemporal_store(v[invb[n]], dst + n);
    }
}

// ---------- Fallback: R8 direct kernel (used when ws is too small) ----------
__global__ __launch_bounds__(256) void interp_direct_kernel(
    const float* __restrict__ feature,
    const float* __restrict__ keypoints,
    float* __restrict__ out)
{
    int bid   = blockIdx.x;
    int xcd   = bid & (NXCD - 1);
    int slot  = bid >> 3;
    int gloc  = slot >> 4;
    int j     = slot & 15;
    int g     = gloc * NXCD + xcd;
    int b     = g >> 5;
    int c0    = (g & 31) * CPT;
    int n     = j * 256 + threadIdx.x;

    const float* kp = keypoints + ((size_t)(b * NKP + n)) * 2;
    float kx = kp[0] * INV_RATIO;
    float ky = kp[1] * INV_RATIO;

    float fx = fmaxf(floorf(kx), 0.0f);
    float fy = fmaxf(floorf(ky), 0.0f);
    int x0 = (int)fx, y0 = (int)fy;

    float ux = kx - fx, uy = ky - fy;
    float lx = 1.0f - ux, ly = 1.0f - uy;

    bool selx = (x0 >= WW - 1);
    bool sely = (y0 >= HH - 1);
    int xp = selx ? (WW - 2) : x0;
    int yp = sely ? (HH - 2) : y0;
    float wlx = selx ? 0.0f : lx, wux = selx ? 1.0f : ux;
    float wly = sely ? 0.0f : ly, wuy = sely ? 1.0f : uy;

    float mask = 0.5f * ((kx > 1e-10f ? 1.0f : 0.0f) + (ky > 1e-10f ? 1.0f : 0.0f));
    float w00 = wlx * wly * mask, w01 = wux * wly * mask;
    float w10 = wlx * wuy * mask, w11 = wux * wuy * mask;

    int i0 = yp * WW + xp;
    int i1 = i0 + WW;

    const float* f = feature + ((size_t)(b * CC + c0)) * (HH * WW);

    fpair r0[CPT], r1[CPT];
    #pragma unroll
    for (int k = 0; k < CPT; ++k) {
        const float* fc = f + (size_t)k * (HH * WW);
        __builtin_memcpy(&r0[k], fc + i0, sizeof(fpair));
        __builtin_memcpy(&r1[k], fc + i1, sizeof(fpair));
    }

    float* o = out + ((size_t)(b * CC + c0)) * NKP + n;
    #pragma unroll
    for (int k = 0; k < CPT; ++k) {
        float val = w00 * r0[k].x + w01 * r0[k].y
                  + w10 * r1[k].x + w11 * r1[k].y;
        __builtin_nontemporal_store(val, o + (size_t)k * NKP);
    }
}

extern "C" void kernel_launch(void* const* d_in, const int* in_sizes, int n_in,
                              void* d_out, int out_size, void* d_ws, size_t ws_size,
                              hipStream_t stream) {
    const float* feature   = (const float*)d_in[0];
    const float* keypoints = (const float*)d_in[1];
    float* out = (float*)d_out;

    if (ws_size < WS_NEEDED) {
        const int grid = BB * (CC / CPT) * (NKP / 256);  // 2048
        interp_direct_kernel<<<grid, 256, 0, stream>>>(feature, keypoints, out);
        return;
    }

    char* ws = (char*)d_ws;
    float*    sorted_kp  = (float*)ws;
    unsigned* inv        = (unsigned*)(ws + O_INV);
    float*    out_sorted = (float*)(ws + O_VS);

    sort_kernel<<<BB, 1024, 0, stream>>>(keypoints, sorted_kp, inv);
    gather_kernel<<<BB * (CC / CPT) * (NKP / 256), 256, 0, stream>>>(feature, sorted_kp, out_sorted);
    permute_kernel<<<BB * CC, 256, 0, stream>>>(out_sorted, inv, out);
}

// Round 11
// 32.535 us; speedup vs baseline: 1.1969x; 1.1969x over previous
//
#include <hip/hip_runtime.h>

// Problem constants (from reference setup_inputs)
#define BB 4
#define CC 128
#define HH 256
#define WW 256
#define NKP 4096
#define INV_RATIO (1.0f / 16.0f)
#define KPT 4                 // keypoints per thread
#define CPT 2                 // channels per thread
#define NXCD 8

typedef float fpair __attribute__((ext_vector_type(2)));
typedef float f4    __attribute__((ext_vector_type(4)));

// Grid: BB * (CC/CPT) * (NKP/(256*KPT)) = 4 * 64 * 4 = 1024 blocks of 256.
// Thread = 4 consecutive keypoints x 2 channels (8 outputs):
//   kp loads: 2x dwordx4 (32B, 16B-aligned since n0 % 4 == 0)
//   gathers : 16x dwordx2 (row-pair per kp per channel, R8 scheme)
//   stores  : 2x dwordx4 NT (coalesced, 16B-aligned)
// VMEM/output = 20/8 = 2.5 vs R8's 3.25.
// Swizzle: group g (= b*64 + c0/2) pinned to XCD g%8; 256 groups, 256%8==0
// -> bijective. Each 2-map group (512KB) fetched into exactly one L2.
__global__ __launch_bounds__(256) void interp_kernel(
    const float* __restrict__ feature,     // B x C x H x W
    const float* __restrict__ keypoints,   // B x N x 2
    float* __restrict__ out)               // B x C x N
{
    int bid  = blockIdx.x;         // 0..1023
    int xcd  = bid & (NXCD - 1);
    int slot = bid >> 3;           // 0..127
    int gloc = slot >> 2;          // 0..31
    int j    = slot & 3;           // 0..3
    int g    = gloc * NXCD + xcd;  // 0..255
    int b    = g >> 6;
    int c0   = (g & 63) * CPT;
    int n0   = j * 1024 + threadIdx.x * KPT;

    // 4 keypoints = 8 floats = 2x dwordx4
    const float* kpp = keypoints + ((size_t)(b * NKP + n0)) * 2;
    f4 kpa, kpb;
    __builtin_memcpy(&kpa, kpp,     sizeof(f4));
    __builtin_memcpy(&kpb, kpp + 4, sizeof(f4));

    float kxs[KPT] = { kpa.x * INV_RATIO, kpa.z * INV_RATIO,
                       kpb.x * INV_RATIO, kpb.z * INV_RATIO };
    float kys[KPT] = { kpa.y * INV_RATIO, kpa.w * INV_RATIO,
                       kpb.y * INV_RATIO, kpb.w * INV_RATIO };

    const float* f0 = feature + ((size_t)(b * CC + c0)) * (HH * WW);
    const float* f1 = f0 + HH * WW;

    float w00[KPT], w01[KPT], w10[KPT], w11[KPT];
    int   i0[KPT], i1[KPT];
    #pragma unroll
    for (int k = 0; k < KPT; ++k) {
        float kx = kxs[k], ky = kys[k];
        float fx = fmaxf(floorf(kx), 0.0f);
        float fy = fmaxf(floorf(ky), 0.0f);
        int x0 = (int)fx, y0 = (int)fy;

        float ux = kx - fx, uy = ky - fy;
        float lx = 1.0f - ux, ly = 1.0f - uy;

        bool selx = (x0 >= WW - 1);
        bool sely = (y0 >= HH - 1);
        int xp = selx ? (WW - 2) : x0;
        int yp = sely ? (HH - 2) : y0;
        float wlx = selx ? 0.0f : lx, wux = selx ? 1.0f : ux;
        float wly = sely ? 0.0f : ly, wuy = sely ? 1.0f : uy;

        float mask = 0.5f * ((kx > 1e-10f ? 1.0f : 0.0f) + (ky > 1e-10f ? 1.0f : 0.0f));
        w00[k] = wlx * wly * mask; w01[k] = wux * wly * mask;
        w10[k] = wlx * wuy * mask; w11[k] = wux * wuy * mask;

        i0[k] = yp * WW + xp;
        i1[k] = i0[k] + WW;
    }

    // 16 independent row-pair gathers (issue all before the FLOPs)
    fpair a0[KPT], a1[KPT], b0[KPT], b1[KPT];
    #pragma unroll
    for (int k = 0; k < KPT; ++k) {
        __builtin_memcpy(&a0[k], f0 + i0[k], sizeof(fpair));
        __builtin_memcpy(&a1[k], f0 + i1[k], sizeof(fpair));
        __builtin_memcpy(&b0[k], f1 + i0[k], sizeof(fpair));
        __builtin_memcpy(&b1[k], f1 + i1[k], sizeof(fpair));
    }

    f4 r0, r1;
    #pragma unroll
    for (int k = 0; k < KPT; ++k) {
        r0[k] = w00[k] * a0[k].x + w01[k] * a0[k].y
              + w10[k] * a1[k].x + w11[k] * a1[k].y;
        r1[k] = w00[k] * b0[k].x + w01[k] * b0[k].y
              + w10[k] * b1[k].x + w11[k] * b1[k].y;
    }

    float* o = out + ((size_t)(b * CC + c0)) * NKP + n0;   // 16B-aligned
    __builtin_nontemporal_store(r0, (f4*)o);
    __builtin_nontemporal_store(r1, (f4*)(o + NKP));
}

extern "C" void kernel_launch(void* const* d_in, const int* in_sizes, int n_in,
                              void* d_out, int out_size, void* d_ws, size_t ws_size,
                              hipStream_t stream) {
    const float* feature   = (const float*)d_in[0];
    const float* keypoints = (const float*)d_in[1];
    float* out = (float*)d_out;

    const int grid = BB * (CC / CPT) * (NKP / (256 * KPT));  // 1024
    interp_kernel<<<grid, 256, 0, stream>>>(feature, keypoints, out);
}